// Round 1
// baseline (1522.870 us; speedup 1.0000x reference)
//
#include <hip/hip_runtime.h>

// TTGNN: 2-layer GAT-style transformer conv, N=20000 nodes, E=120000 edges,
// D=1024, H=8 heads, C=128. Key insight: e_all @ W_e collapses to a 5-row
// lookup table M[t] = edge_type_emb[t] @ W_e (+ per-node mix for self-loops),
// so the only big GEMMs are h@W_l, h@W_r (x2 layers) and h@W_out: 5 x 42 GF.
// GEMMs run as bf16 MFMA 16x16x32, 128x128 tile. Attention path is CSR-based,
// atomic-free, with softmax+aggregate+bias+ELU+residual+LayerNorm fused per node.

#define NN 20000
#define NE 120000
#define DD 1024
#define NH 8

typedef __attribute__((ext_vector_type(4))) float f32x4;
typedef __bf16 bf16x8 __attribute__((ext_vector_type(8)));

__device__ __forceinline__ unsigned short f2bf(float f) {
  unsigned int u = __float_as_uint(f);
  u += 0x7FFFu + ((u >> 16) & 1u);   // round-to-nearest-even
  return (unsigned short)(u >> 16);
}

// ---------------- CSR build ----------------

__global__ __launch_bounds__(256) void count_kernel(
    const int* __restrict__ EI, const int* __restrict__ eattr, int* __restrict__ cnt) {
  int e = blockIdx.x * 256 + threadIdx.x;
  if (e < NE) {
    int d = EI[NE + e];
    int t = eattr[e];
    atomicAdd(&cnt[d * 5 + t], 1);
  }
}

__global__ __launch_bounds__(256) void scan_kernel(
    const int* __restrict__ cnt, int* __restrict__ rowptr, int* __restrict__ cursor) {
  __shared__ int wsum[4];
  __shared__ int carry_s;
  int tid = threadIdx.x, lane = tid & 63, wv = tid >> 6;
  if (tid == 0) carry_s = 0;
  __syncthreads();
  for (int base = 0; base < NN; base += 256) {
    int n = base + tid;
    int d = 0;
    if (n < NN) {
      const int* c = cnt + n * 5;
      d = c[0] + c[1] + c[2] + c[3] + c[4];
    }
    int v = d;
    #pragma unroll
    for (int off = 1; off < 64; off <<= 1) {
      int t = __shfl_up(v, off);
      if (lane >= off) v += t;
    }
    if (lane == 63) wsum[wv] = v;
    __syncthreads();
    int woff = 0;
    #pragma unroll
    for (int w = 0; w < 4; ++w) if (w < wv) woff += wsum[w];
    int carry = carry_s;
    int excl = carry + woff + v - d;   // exclusive prefix
    if (n < NN) { rowptr[n] = excl; cursor[n] = excl; }
    __syncthreads();
    if (tid == 0) carry_s = carry + wsum[0] + wsum[1] + wsum[2] + wsum[3];
    __syncthreads();
  }
  if (threadIdx.x == 0) rowptr[NN] = carry_s;
}

__global__ __launch_bounds__(256) void scatter_kernel(
    const int* __restrict__ EI, int* __restrict__ cursor, int* __restrict__ eids) {
  int e = blockIdx.x * 256 + threadIdx.x;
  if (e < NE) {
    int d = EI[NE + e];
    int pos = atomicAdd(&cursor[d], 1);
    eids[pos] = e;
  }
}

// ---------------- h0 = x + node_type_emb[node_types] ----------------

__global__ __launch_bounds__(256) void init_h_kernel(
    const float* __restrict__ x, const int* __restrict__ ntypes,
    const float* __restrict__ ntemb, float* __restrict__ h,
    unsigned short* __restrict__ hb) {
  int idx = blockIdx.x * 256 + threadIdx.x;   // float4 index, exactly NN*256 of them
  int n = idx >> 8;
  int d4 = idx & 255;
  int t = ntypes[n];
  float4 xv = ((const float4*)x)[idx];
  float4 ev = ((const float4*)ntemb)[t * 256 + d4];
  float4 o;
  o.x = xv.x + ev.x; o.y = xv.y + ev.y; o.z = xv.z + ev.z; o.w = xv.w + ev.w;
  ((float4*)h)[idx] = o;
  ushort4 hv;
  hv.x = f2bf(o.x); hv.y = f2bf(o.y); hv.z = f2bf(o.z); hv.w = f2bf(o.w);
  ((ushort4*)hb)[idx] = hv;
}

// ---------------- weight transpose + bf16 convert: WT[n][k] = bf16(W[k][n]) ----------------

__global__ __launch_bounds__(256) void transpose_w_kernel(
    const float* __restrict__ W, unsigned short* __restrict__ WT) {
  __shared__ float tile[32][33];
  int tx = threadIdx.x & 31, ty = threadIdx.x >> 5;   // ty 0..7
  int bx = blockIdx.x * 32;   // n base
  int by = blockIdx.y * 32;   // k base
  #pragma unroll
  for (int r = 0; r < 4; ++r)
    tile[ty + r * 8][tx] = W[(size_t)(by + ty + r * 8) * DD + bx + tx];
  __syncthreads();
  #pragma unroll
  for (int r = 0; r < 4; ++r)
    WT[(size_t)(bx + ty + r * 8) * DD + by + tx] = f2bf(tile[tx][ty + r * 8]);
}

// ---------------- M[t] = edge_type_emb[t] @ W_e[l]   (5 x 1024) ----------------

__global__ __launch_bounds__(256) void m_kernel(
    const float* __restrict__ ete, const float* __restrict__ We, float* __restrict__ M) {
  int j = blockIdx.x * 256 + threadIdx.x;
  int t = blockIdx.y;
  float acc = 0.f;
  for (int k = 0; k < DD; ++k)
    acc += ete[t * DD + k] * We[(size_t)k * DD + j];
  M[t * DD + j] = acc;
}

// ---------------- bf16 MFMA GEMM: C[M][1024] = A[M][1024] @ B + bias ----------------
// A: bf16 row-major [M][1024].  BT: bf16 [n][k] (i.e. B transposed).
// mode 0: C = acc + bias.   mode 1: C = resid + gate*(acc + bias).

__global__ __launch_bounds__(256) void gemm_bf16(
    const unsigned short* __restrict__ A, const unsigned short* __restrict__ BT,
    const float* __restrict__ bias, const float* __restrict__ resid,
    const float* __restrict__ gatep, float* __restrict__ Cout, int M, int mode) {
  __shared__ unsigned short lsA[128 * 40];
  __shared__ unsigned short lsB[128 * 40];
  const int tid = threadIdx.x;
  const int lane = tid & 63;
  const int wv = tid >> 6;
  const int wm = wv & 1, wn = wv >> 1;
  const int bm = blockIdx.y, bn = blockIdx.x;
  const int row0 = bm * 128, col0 = bn * 128;
  const int l15 = lane & 15, quad = lane >> 4;

  f32x4 acc[4][4];
  #pragma unroll
  for (int mt = 0; mt < 4; ++mt)
    #pragma unroll
    for (int nt = 0; nt < 4; ++nt) {
      f32x4 z = {0.f, 0.f, 0.f, 0.f};
      acc[mt][nt] = z;
    }

  const int srow = tid >> 2;          // 0..63
  const int schunk = (tid & 3) * 8;   // element offset within 32-wide k tile

  for (int kk = 0; kk < DD; kk += 32) {
    #pragma unroll
    for (int rep = 0; rep < 2; ++rep) {
      int r = srow + rep * 64;
      int gr = row0 + r;
      uint4 av = {0u, 0u, 0u, 0u};
      if (gr < M) av = *(const uint4*)(A + (size_t)gr * DD + kk + schunk);
      *(uint4*)(lsA + r * 40 + schunk) = av;
      uint4 bv = *(const uint4*)(BT + (size_t)(col0 + r) * DD + kk + schunk);
      *(uint4*)(lsB + r * 40 + schunk) = bv;
    }
    __syncthreads();
    bf16x8 af[4], bfr[4];
    #pragma unroll
    for (int mt = 0; mt < 4; ++mt)
      af[mt] = *(const bf16x8*)(lsA + (wm * 64 + mt * 16 + l15) * 40 + quad * 8);
    #pragma unroll
    for (int nt = 0; nt < 4; ++nt)
      bfr[nt] = *(const bf16x8*)(lsB + (wn * 64 + nt * 16 + l15) * 40 + quad * 8);
    #pragma unroll
    for (int mt = 0; mt < 4; ++mt)
      #pragma unroll
      for (int nt = 0; nt < 4; ++nt)
        acc[mt][nt] = __builtin_amdgcn_mfma_f32_16x16x32_bf16(af[mt], bfr[nt], acc[mt][nt], 0, 0, 0);
    __syncthreads();
  }

  float g = (mode == 1) ? gatep[0] : 0.f;
  #pragma unroll
  for (int mt = 0; mt < 4; ++mt) {
    #pragma unroll
    for (int r = 0; r < 4; ++r) {
      int grow = row0 + wm * 64 + mt * 16 + quad * 4 + r;
      if (grow >= M) continue;
      #pragma unroll
      for (int nt = 0; nt < 4; ++nt) {
        int gcol = col0 + wn * 64 + nt * 16 + l15;
        float v = acc[mt][nt][r] + bias[gcol];
        if (mode == 1) v = resid[(size_t)grow * DD + gcol] + g * v;
        Cout[(size_t)grow * DD + gcol] = v;
      }
    }
  }
}

// ---------------- logits[e][h] = sum_c lrelu(xl[src]+xr[dst]+ee)*att ----------------
// One wave per edge. e in [0,NE): real edges, ee = M[edge_attr[e]].
// e in [NE, NE+NN): self-loops, ee = sum_t (count[n,t]/deg)*M[t].

__global__ __launch_bounds__(256) void logits_kernel(
    const float* __restrict__ xl, const float* __restrict__ xr,
    const int* __restrict__ EI, const int* __restrict__ eattr,
    const float* __restrict__ Mbuf, const float* __restrict__ attl,
    const int* __restrict__ cnt, float* __restrict__ logits) {
  __shared__ float Ms[6 * 1024];   // M[5][1024] + att[1024]
  {
    float4* Ms4 = (float4*)Ms;
    const float4* Mb4 = (const float4*)Mbuf;
    const float4* at4 = (const float4*)attl;
    for (int i = threadIdx.x; i < 1536; i += 256)
      Ms4[i] = (i < 1280) ? Mb4[i] : at4[i - 1280];
  }
  __syncthreads();
  int lane = threadIdx.x & 63, wv = threadIdx.x >> 6;
  int i0 = lane * 16;
  const float4* attp = (const float4*)(Ms + 5 * 1024 + i0);
  int nwaves = gridDim.x * 4;
  for (int e = blockIdx.x * 4 + wv; e < NE + NN; e += nwaves) {
    int srow, drow;
    float4 m[4];
    if (e < NE) {
      srow = EI[e];
      drow = EI[NE + e];
      const float4* mp = (const float4*)(Ms + eattr[e] * 1024 + i0);
      #pragma unroll
      for (int j = 0; j < 4; ++j) m[j] = mp[j];
    } else {
      int n = e - NE;
      srow = drow = n;
      const int* c = cnt + n * 5;
      int c0 = c[0], c1 = c[1], c2 = c[2], c3 = c[3], c4 = c[4];
      float inv = 1.f / fmaxf((float)(c0 + c1 + c2 + c3 + c4), 1.f);
      float w0 = c0 * inv, w1 = c1 * inv, w2 = c2 * inv, w3 = c3 * inv, w4 = c4 * inv;
      const float4* p0 = (const float4*)(Ms + 0 * 1024 + i0);
      const float4* p1 = (const float4*)(Ms + 1 * 1024 + i0);
      const float4* p2 = (const float4*)(Ms + 2 * 1024 + i0);
      const float4* p3 = (const float4*)(Ms + 3 * 1024 + i0);
      const float4* p4 = (const float4*)(Ms + 4 * 1024 + i0);
      #pragma unroll
      for (int j = 0; j < 4; ++j) {
        float4 a0 = p0[j], a1 = p1[j], a2 = p2[j], a3 = p3[j], a4 = p4[j];
        m[j].x = w0 * a0.x + w1 * a1.x + w2 * a2.x + w3 * a3.x + w4 * a4.x;
        m[j].y = w0 * a0.y + w1 * a1.y + w2 * a2.y + w3 * a3.y + w4 * a4.y;
        m[j].z = w0 * a0.z + w1 * a1.z + w2 * a2.z + w3 * a3.z + w4 * a4.z;
        m[j].w = w0 * a0.w + w1 * a1.w + w2 * a2.w + w3 * a3.w + w4 * a4.w;
      }
    }
    const float4* xlp = (const float4*)(xl + (size_t)srow * DD + i0);
    const float4* xrp = (const float4*)(xr + (size_t)drow * DD + i0);
    float partial = 0.f;
    #pragma unroll
    for (int j = 0; j < 4; ++j) {
      float4 a = xlp[j], b = xrp[j], at = attp[j];
      float vx = a.x + b.x + m[j].x; vx = vx >= 0.f ? vx : 0.2f * vx;
      float vy = a.y + b.y + m[j].y; vy = vy >= 0.f ? vy : 0.2f * vy;
      float vz = a.z + b.z + m[j].z; vz = vz >= 0.f ? vz : 0.2f * vz;
      float vw = a.w + b.w + m[j].w; vw = vw >= 0.f ? vw : 0.2f * vw;
      partial += vx * at.x + vy * at.y + vz * at.z + vw * at.w;
    }
    partial += __shfl_xor(partial, 1);
    partial += __shfl_xor(partial, 2);
    partial += __shfl_xor(partial, 4);
    if ((lane & 7) == 0) logits[(size_t)e * NH + (lane >> 3)] = partial;
  }
}

// ---------------- per-node: softmax over incoming edges, aggregate, bias, ELU,
// residual, LayerNorm. Writes h (fp32) and hb (bf16). One block per node. ----------------

__global__ __launch_bounds__(256) void agg_ln_kernel(
    const float* __restrict__ xl, const float* __restrict__ logits,
    const int* __restrict__ EI, const int* __restrict__ rowptr,
    const int* __restrict__ eids, const float* __restrict__ biasl,
    const float* __restrict__ gammal, const float* __restrict__ betal,
    float* __restrict__ h, unsigned short* __restrict__ hb) {
  int n = blockIdx.x;
  int tid = threadIdx.x;
  __shared__ float sm[16];   // mx[8], invden[8]
  __shared__ float red[8];   // cross-wave LN reduce
  int beg = rowptr[n], end = rowptr[n + 1];
  if (tid < 8) {
    int hh = tid;
    float self_lg = logits[(size_t)(NE + n) * NH + hh];
    float mx = self_lg;
    for (int idx = beg; idx < end; ++idx)
      mx = fmaxf(mx, logits[(size_t)eids[idx] * NH + hh]);
    float den = __expf(self_lg - mx);
    for (int idx = beg; idx < end; ++idx)
      den += __expf(logits[(size_t)eids[idx] * NH + hh] - mx);
    sm[hh] = mx;
    sm[8 + hh] = 1.f / den;
  }
  __syncthreads();
  int i = tid * 4;
  int hh = i >> 7;
  float mx = sm[hh], invd = sm[8 + hh];
  float ax = 0.f, ay = 0.f, az = 0.f, aw = 0.f;
  for (int idx = beg; idx < end; ++idx) {
    int eid = eids[idx];
    int src = EI[eid];
    float a = __expf(logits[(size_t)eid * NH + hh] - mx) * invd;
    float4 v = *(const float4*)(xl + (size_t)src * DD + i);
    ax += a * v.x; ay += a * v.y; az += a * v.z; aw += a * v.w;
  }
  {
    float a = __expf(logits[(size_t)(NE + n) * NH + hh] - mx) * invd;
    float4 v = *(const float4*)(xl + (size_t)n * DD + i);
    ax += a * v.x; ay += a * v.y; az += a * v.z; aw += a * v.w;
  }
  float4 b4 = *(const float4*)(biasl + i);
  ax += b4.x; ay += b4.y; az += b4.z; aw += b4.w;
  // ELU
  ax = ax > 0.f ? ax : (__expf(ax) - 1.f);
  ay = ay > 0.f ? ay : (__expf(ay) - 1.f);
  az = az > 0.f ? az : (__expf(az) - 1.f);
  aw = aw > 0.f ? aw : (__expf(aw) - 1.f);
  // residual
  float4 hv = *(const float4*)(h + (size_t)n * DD + i);
  float yx = ax + hv.x, yy = ay + hv.y, yz = az + hv.z, yw = aw + hv.w;
  // LayerNorm reduce
  float s1 = yx + yy + yz + yw;
  float s2 = yx * yx + yy * yy + yz * yz + yw * yw;
  #pragma unroll
  for (int off = 1; off < 64; off <<= 1) {
    s1 += __shfl_xor(s1, off);
    s2 += __shfl_xor(s2, off);
  }
  int lane = tid & 63, wv = tid >> 6;
  if (lane == 0) { red[wv] = s1; red[4 + wv] = s2; }
  __syncthreads();
  s1 = red[0] + red[1] + red[2] + red[3];
  s2 = red[4] + red[5] + red[6] + red[7];
  float mu = s1 * (1.f / 1024.f);
  float var = s2 * (1.f / 1024.f) - mu * mu;
  float rs = rsqrtf(var + 1e-5f);
  float4 g4 = *(const float4*)(gammal + i);
  float4 be4 = *(const float4*)(betal + i);
  float ox = (yx - mu) * rs * g4.x + be4.x;
  float oy = (yy - mu) * rs * g4.y + be4.y;
  float oz = (yz - mu) * rs * g4.z + be4.z;
  float ow = (yw - mu) * rs * g4.w + be4.w;
  float4 o4; o4.x = ox; o4.y = oy; o4.z = oz; o4.w = ow;
  *(float4*)(h + (size_t)n * DD + i) = o4;
  ushort4 hbv;
  hbv.x = f2bf(ox); hbv.y = f2bf(oy); hbv.z = f2bf(oz); hbv.w = f2bf(ow);
  *(ushort4*)(hb + (size_t)n * DD + i) = hbv;
}

// ---------------- launcher ----------------

extern "C" void kernel_launch(void* const* d_in, const int* in_sizes, int n_in,
                              void* d_out, int out_size, void* d_ws, size_t ws_size,
                              hipStream_t stream) {
  (void)in_sizes; (void)n_in; (void)out_size; (void)ws_size;
  const float* x      = (const float*)d_in[0];
  const int*   EI     = (const int*)d_in[1];
  const int*   eattr  = (const int*)d_in[2];
  const int*   ntypes = (const int*)d_in[3];
  const float* ntemb  = (const float*)d_in[4];
  const float* etemb  = (const float*)d_in[5];
  const float* W_l    = (const float*)d_in[6];
  const float* b_l    = (const float*)d_in[7];
  const float* W_r    = (const float*)d_in[8];
  const float* b_r    = (const float*)d_in[9];
  const float* W_e    = (const float*)d_in[10];
  const float* att    = (const float*)d_in[11];
  const float* bias   = (const float*)d_in[12];
  const float* gamma  = (const float*)d_in[13];
  const float* beta   = (const float*)d_in[14];
  const float* W_out  = (const float*)d_in[15];
  const float* b_out  = (const float*)d_in[16];
  const float* gate   = (const float*)d_in[17];
  float* out = (float*)d_out;

  char* ws = (char*)d_ws;
  size_t off = 0;
  auto alloc = [&](size_t bytes) {
    char* p = ws + off;
    off = (off + bytes + 255) & ~(size_t)255;
    return p;
  };
  float*          h       = (float*)alloc((size_t)NN * DD * 4);
  float*          xr      = (float*)alloc((size_t)NN * DD * 4);
  unsigned short* hb      = (unsigned short*)alloc((size_t)NN * DD * 2);
  unsigned short* WT0     = (unsigned short*)alloc((size_t)DD * DD * 2);
  unsigned short* WT1     = (unsigned short*)alloc((size_t)DD * DD * 2);
  unsigned short* WT2     = (unsigned short*)alloc((size_t)DD * DD * 2);
  float*          Mbuf    = (float*)alloc((size_t)5 * DD * 4);
  float*          logitsb = (float*)alloc((size_t)(NE + NN) * NH * 4);
  int*            countb  = (int*)alloc((size_t)NN * 5 * 4);
  int*            rowptr  = (int*)alloc((size_t)(NN + 1) * 4);
  int*            cursor  = (int*)alloc((size_t)NN * 4);
  int*            eids    = (int*)alloc((size_t)NE * 4);
  float*          xl      = out;   // reuse d_out as xl scratch; final GEMM overwrites it

  hipMemsetAsync(countb, 0, (size_t)NN * 5 * 4, stream);
  count_kernel<<<(NE + 255) / 256, 256, 0, stream>>>(EI, eattr, countb);
  scan_kernel<<<1, 256, 0, stream>>>(countb, rowptr, cursor);
  scatter_kernel<<<(NE + 255) / 256, 256, 0, stream>>>(EI, cursor, eids);
  init_h_kernel<<<NN, 256, 0, stream>>>(x, ntypes, ntemb, h, hb);

  dim3 tgrid(DD / 32, DD / 32);
  dim3 ggrid(DD / 128, (NN + 127) / 128);
  for (int l = 0; l < 2; ++l) {
    transpose_w_kernel<<<tgrid, 256, 0, stream>>>(W_l + (size_t)l * DD * DD, WT0);
    transpose_w_kernel<<<tgrid, 256, 0, stream>>>(W_r + (size_t)l * DD * DD, WT1);
    m_kernel<<<dim3(DD / 256, 5), 256, 0, stream>>>(etemb, W_e + (size_t)l * DD * DD, Mbuf);
    gemm_bf16<<<ggrid, 256, 0, stream>>>(hb, WT0, b_l + l * DD, nullptr, nullptr, xl, NN, 0);
    gemm_bf16<<<ggrid, 256, 0, stream>>>(hb, WT1, b_r + l * DD, nullptr, nullptr, xr, NN, 0);
    logits_kernel<<<2048, 256, 0, stream>>>(xl, xr, EI, eattr, Mbuf, att + l * DD, countb, logitsb);
    agg_ln_kernel<<<NN, 256, 0, stream>>>(xl, logitsb, EI, rowptr, eids,
                                          bias + l * DD, gamma + l * DD, beta + l * DD, h, hb);
  }
  transpose_w_kernel<<<tgrid, 256, 0, stream>>>(W_out, WT2);
  gemm_bf16<<<ggrid, 256, 0, stream>>>(hb, WT2, b_out, x, gate, out, NN, 1);
}

// Round 2
// 1471.552 us; speedup vs baseline: 1.0349x; 1.0349x over previous
//
#include <hip/hip_runtime.h>

// TTGNN: 2-layer GAT-style transformer conv, N=20000, E=120000, D=1024, H=8, C=128.
// R2: (a) GEMMs use global_load_lds width-16 staging (m97 structure) and the two
// layer GEMMs (h@W_l, h@W_r) are fused into one M x 2048 x 1024 GEMM sharing the
// A operand. (b) logits+softmax+aggregate fused into one per-node kernel with
// online softmax -- xl[src] rows are gathered exactly once per edge.

#define NN 20000
#define NE 120000
#define DD 1024
#define NH 8

typedef __attribute__((ext_vector_type(4))) float f32x4;
typedef __bf16 bf16x8 __attribute__((ext_vector_type(8)));

__device__ __forceinline__ unsigned short f2bf(float f) {
  unsigned int u = __float_as_uint(f);
  u += 0x7FFFu + ((u >> 16) & 1u);   // round-to-nearest-even
  return (unsigned short)(u >> 16);
}

// ---------------- CSR build ----------------

__global__ __launch_bounds__(256) void count_kernel(
    const int* __restrict__ EI, const int* __restrict__ eattr, int* __restrict__ cnt) {
  int e = blockIdx.x * 256 + threadIdx.x;
  if (e < NE) {
    int d = EI[NE + e];
    int t = eattr[e];
    atomicAdd(&cnt[d * 5 + t], 1);
  }
}

__global__ __launch_bounds__(256) void scan_kernel(
    const int* __restrict__ cnt, int* __restrict__ rowptr, int* __restrict__ cursor) {
  __shared__ int wsum[4];
  __shared__ int carry_s;
  int tid = threadIdx.x, lane = tid & 63, wv = tid >> 6;
  if (tid == 0) carry_s = 0;
  __syncthreads();
  for (int base = 0; base < NN; base += 256) {
    int n = base + tid;
    int d = 0;
    if (n < NN) {
      const int* c = cnt + n * 5;
      d = c[0] + c[1] + c[2] + c[3] + c[4];
    }
    int v = d;
    #pragma unroll
    for (int off = 1; off < 64; off <<= 1) {
      int t = __shfl_up(v, off);
      if (lane >= off) v += t;
    }
    if (lane == 63) wsum[wv] = v;
    __syncthreads();
    int woff = 0;
    #pragma unroll
    for (int w = 0; w < 4; ++w) if (w < wv) woff += wsum[w];
    int carry = carry_s;
    int excl = carry + woff + v - d;
    if (n < NN) { rowptr[n] = excl; cursor[n] = excl; }
    __syncthreads();
    if (tid == 0) carry_s = carry + wsum[0] + wsum[1] + wsum[2] + wsum[3];
    __syncthreads();
  }
  if (threadIdx.x == 0) rowptr[NN] = carry_s;
}

__global__ __launch_bounds__(256) void scatter_kernel(
    const int* __restrict__ EI, int* __restrict__ cursor, int* __restrict__ eids) {
  int e = blockIdx.x * 256 + threadIdx.x;
  if (e < NE) {
    int d = EI[NE + e];
    int pos = atomicAdd(&cursor[d], 1);
    eids[pos] = e;
  }
}

// ---------------- h0 = x + node_type_emb[node_types] ----------------

__global__ __launch_bounds__(256) void init_h_kernel(
    const float* __restrict__ x, const int* __restrict__ ntypes,
    const float* __restrict__ ntemb, float* __restrict__ h,
    unsigned short* __restrict__ hb) {
  int idx = blockIdx.x * 256 + threadIdx.x;
  int n = idx >> 8;
  int d4 = idx & 255;
  int t = ntypes[n];
  float4 xv = ((const float4*)x)[idx];
  float4 ev = ((const float4*)ntemb)[t * 256 + d4];
  float4 o;
  o.x = xv.x + ev.x; o.y = xv.y + ev.y; o.z = xv.z + ev.z; o.w = xv.w + ev.w;
  ((float4*)h)[idx] = o;
  ushort4 hv;
  hv.x = f2bf(o.x); hv.y = f2bf(o.y); hv.z = f2bf(o.z); hv.w = f2bf(o.w);
  ((ushort4*)hb)[idx] = hv;
}

// ---------------- weight transpose + bf16: WT[n][k] = bf16(W[k][n]) ----------------

__global__ __launch_bounds__(256) void transpose_w_kernel(
    const float* __restrict__ W, unsigned short* __restrict__ WT) {
  __shared__ float tile[32][33];
  int tx = threadIdx.x & 31, ty = threadIdx.x >> 5;
  int bx = blockIdx.x * 32;   // n base
  int by = blockIdx.y * 32;   // k base
  #pragma unroll
  for (int r = 0; r < 4; ++r)
    tile[ty + r * 8][tx] = W[(size_t)(by + ty + r * 8) * DD + bx + tx];
  __syncthreads();
  #pragma unroll
  for (int r = 0; r < 4; ++r)
    WT[(size_t)(bx + ty + r * 8) * DD + by + tx] = f2bf(tile[tx][ty + r * 8]);
}

// ---------------- M[t] = edge_type_emb[t] @ W_e[l]   (5 x 1024) ----------------

__global__ __launch_bounds__(256) void m_kernel(
    const float* __restrict__ ete, const float* __restrict__ We, float* __restrict__ M) {
  int j = blockIdx.x * 256 + threadIdx.x;
  int t = blockIdx.y;
  float acc = 0.f;
  for (int k = 0; k < DD; ++k)
    acc += ete[t * DD + k] * We[(size_t)k * DD + j];
  M[t * DD + j] = acc;
}

// ---------------- bf16 MFMA GEMM, global_load_lds staging (m97 structure) ----
// A: bf16 [M][1024].  BT: bf16 [Ncols][1024] (B transposed), Ncols = 128*gridDim.x.
// mode 0 (dual): bn<8 -> C0 (+bias0), bn>=8 -> C1 (+bias1), local col = gcol-1024.
// mode 1 (final): C0 = resid + gate*(acc + bias0).

__global__ __launch_bounds__(256) void gemm_bf16(
    const unsigned short* __restrict__ A, const unsigned short* __restrict__ BT,
    const float* __restrict__ bias0, const float* __restrict__ bias1,
    float* __restrict__ C0, float* __restrict__ C1,
    const float* __restrict__ resid, const float* __restrict__ gatep,
    int M, int mode) {
  __shared__ unsigned short lsA[128 * 32];
  __shared__ unsigned short lsB[128 * 32];
  const int tid = threadIdx.x;
  const int lane = tid & 63;
  const int wv = tid >> 6;
  const int wm = wv & 1, wn = wv >> 1;
  const int bm = blockIdx.y, bn = blockIdx.x;
  const int row0 = bm * 128, col0 = bn * 128;
  const int l15 = lane & 15, quad = lane >> 4;

  f32x4 acc[4][4];
  #pragma unroll
  for (int mt = 0; mt < 4; ++mt)
    #pragma unroll
    for (int nt = 0; nt < 4; ++nt) {
      f32x4 z = {0.f, 0.f, 0.f, 0.f};
      acc[mt][nt] = z;
    }

  const int r_in = lane >> 2;            // 0..15
  const int kchunk = (lane & 3) * 8;     // bf16-element offset within 32-wide K

  for (int kk = 0; kk < DD; kk += 32) {
    #pragma unroll
    for (int j = 0; j < 2; ++j) {
      int r = wv * 32 + j * 16;                  // wave-uniform row base of this call
      int gr = row0 + r + r_in;
      if (gr > M - 1) gr = M - 1;                // clamp tail (outputs masked at store)
      const unsigned short* gpA = A + (size_t)gr * DD + kk + kchunk;
      __builtin_amdgcn_global_load_lds(
          (const __attribute__((address_space(1))) unsigned int*)gpA,
          (__attribute__((address_space(3))) unsigned int*)(lsA + r * 32), 16, 0, 0);
      const unsigned short* gpB = BT + (size_t)(col0 + r + r_in) * DD + kk + kchunk;
      __builtin_amdgcn_global_load_lds(
          (const __attribute__((address_space(1))) unsigned int*)gpB,
          (__attribute__((address_space(3))) unsigned int*)(lsB + r * 32), 16, 0, 0);
    }
    __syncthreads();
    bf16x8 af[4], bfr[4];
    #pragma unroll
    for (int mt = 0; mt < 4; ++mt)
      af[mt] = *(const bf16x8*)(lsA + (wm * 64 + mt * 16 + l15) * 32 + quad * 8);
    #pragma unroll
    for (int nt = 0; nt < 4; ++nt)
      bfr[nt] = *(const bf16x8*)(lsB + (wn * 64 + nt * 16 + l15) * 32 + quad * 8);
    #pragma unroll
    for (int mt = 0; mt < 4; ++mt)
      #pragma unroll
      for (int nt = 0; nt < 4; ++nt)
        acc[mt][nt] = __builtin_amdgcn_mfma_f32_16x16x32_bf16(af[mt], bfr[nt], acc[mt][nt], 0, 0, 0);
    __syncthreads();
  }

  float* Cp = C0;
  const float* bp = bias0;
  int coff = 0;
  if (mode == 0 && bn >= 8) { Cp = C1; bp = bias1; coff = 1024; }
  float g = (mode == 1) ? gatep[0] : 0.f;
  #pragma unroll
  for (int mt = 0; mt < 4; ++mt) {
    #pragma unroll
    for (int r = 0; r < 4; ++r) {
      int grow = row0 + wm * 64 + mt * 16 + quad * 4 + r;
      if (grow >= M) continue;
      #pragma unroll
      for (int nt = 0; nt < 4; ++nt) {
        int c = col0 - coff + wn * 64 + nt * 16 + l15;
        float v = acc[mt][nt][r] + bp[c];
        if (mode == 1) v = resid[(size_t)grow * DD + c] + g * v;
        Cp[(size_t)grow * DD + c] = v;
      }
    }
  }
}

// ---------------- fused attention: per-node online softmax + aggregate + bias +
// ELU + residual + LayerNorm. One block (256 thr) per node; thread owns 4 channels
// (head hh = tid>>5). xl[src] rows gathered exactly once per edge. ----------------

__global__ __launch_bounds__(256) void attn_kernel(
    const float* __restrict__ xl, const float* __restrict__ xr,
    const int* __restrict__ EI, const int* __restrict__ eattr,
    const int* __restrict__ rowptr, const int* __restrict__ eids,
    const int* __restrict__ cnt, const float* __restrict__ Mbuf,
    const float* __restrict__ attl, const float* __restrict__ biasl,
    const float* __restrict__ gammal, const float* __restrict__ betal,
    float* __restrict__ h, unsigned short* __restrict__ hb) {
  int n = blockIdx.x;
  int tid = threadIdx.x;
  int i = tid * 4;
  __shared__ float red[8];

  float4 Mreg[5];
  #pragma unroll
  for (int t = 0; t < 5; ++t) Mreg[t] = *(const float4*)(Mbuf + t * DD + i);
  float4 attv = *(const float4*)(attl + i);
  float4 xrv = *(const float4*)(xr + (size_t)n * DD + i);

  // self-loop edge-emb: mean of incoming edge embeddings
  const int* c = cnt + n * 5;
  int c0 = c[0], c1 = c[1], c2 = c[2], c3 = c[3], c4 = c[4];
  float inv = 1.f / fmaxf((float)(c0 + c1 + c2 + c3 + c4), 1.f);
  float w0 = c0 * inv, w1 = c1 * inv, w2 = c2 * inv, w3 = c3 * inv, w4 = c4 * inv;
  float4 eself;
  eself.x = w0 * Mreg[0].x + w1 * Mreg[1].x + w2 * Mreg[2].x + w3 * Mreg[3].x + w4 * Mreg[4].x;
  eself.y = w0 * Mreg[0].y + w1 * Mreg[1].y + w2 * Mreg[2].y + w3 * Mreg[3].y + w4 * Mreg[4].y;
  eself.z = w0 * Mreg[0].z + w1 * Mreg[1].z + w2 * Mreg[2].z + w3 * Mreg[3].z + w4 * Mreg[4].z;
  eself.w = w0 * Mreg[0].w + w1 * Mreg[1].w + w2 * Mreg[2].w + w3 * Mreg[3].w + w4 * Mreg[4].w;

  float m_run = -__builtin_inff();
  float den = 0.f;
  float ax = 0.f, ay = 0.f, az = 0.f, aw = 0.f;
  int beg = rowptr[n], end = rowptr[n + 1];

  for (int idx = beg; idx <= end; ++idx) {
    int src; float4 ee;
    if (idx < end) {
      int eid = eids[idx];
      src = EI[eid];
      ee = Mreg[eattr[eid]];
    } else {            // self-loop
      src = n;
      ee = eself;
    }
    float4 v = *(const float4*)(xl + (size_t)src * DD + i);
    float sx = v.x + xrv.x + ee.x; sx = sx >= 0.f ? sx : 0.2f * sx;
    float sy = v.y + xrv.y + ee.y; sy = sy >= 0.f ? sy : 0.2f * sy;
    float sz = v.z + xrv.z + ee.z; sz = sz >= 0.f ? sz : 0.2f * sz;
    float sw = v.w + xrv.w + ee.w; sw = sw >= 0.f ? sw : 0.2f * sw;
    float lg = sx * attv.x + sy * attv.y + sz * attv.z + sw * attv.w;
    // reduce over the 32 threads of this head (contiguous 32-lane half-wave)
    lg += __shfl_xor(lg, 1);
    lg += __shfl_xor(lg, 2);
    lg += __shfl_xor(lg, 4);
    lg += __shfl_xor(lg, 8);
    lg += __shfl_xor(lg, 16);
    // online softmax update
    float mn = fmaxf(m_run, lg);
    float fs = __expf(m_run - mn);       // first iter: exp(-inf)=0
    float p = __expf(lg - mn);
    den = den * fs + p;
    ax = ax * fs + p * v.x;
    ay = ay * fs + p * v.y;
    az = az * fs + p * v.z;
    aw = aw * fs + p * v.w;
    m_run = mn;
  }

  float invd = 1.f / den;
  float4 b4 = *(const float4*)(biasl + i);
  ax = ax * invd + b4.x;
  ay = ay * invd + b4.y;
  az = az * invd + b4.z;
  aw = aw * invd + b4.w;
  // ELU
  ax = ax > 0.f ? ax : (__expf(ax) - 1.f);
  ay = ay > 0.f ? ay : (__expf(ay) - 1.f);
  az = az > 0.f ? az : (__expf(az) - 1.f);
  aw = aw > 0.f ? aw : (__expf(aw) - 1.f);
  // residual
  float4 hv = *(const float4*)(h + (size_t)n * DD + i);
  float yx = ax + hv.x, yy = ay + hv.y, yz = az + hv.z, yw = aw + hv.w;
  // LayerNorm
  float s1 = yx + yy + yz + yw;
  float s2 = yx * yx + yy * yy + yz * yz + yw * yw;
  #pragma unroll
  for (int off = 1; off < 64; off <<= 1) {
    s1 += __shfl_xor(s1, off);
    s2 += __shfl_xor(s2, off);
  }
  int lane = tid & 63, wv = tid >> 6;
  if (lane == 0) { red[wv] = s1; red[4 + wv] = s2; }
  __syncthreads();
  s1 = red[0] + red[1] + red[2] + red[3];
  s2 = red[4] + red[5] + red[6] + red[7];
  float mu = s1 * (1.f / 1024.f);
  float var = s2 * (1.f / 1024.f) - mu * mu;
  float rs = rsqrtf(var + 1e-5f);
  float4 g4 = *(const float4*)(gammal + i);
  float4 be4 = *(const float4*)(betal + i);
  float ox = (yx - mu) * rs * g4.x + be4.x;
  float oy = (yy - mu) * rs * g4.y + be4.y;
  float oz = (yz - mu) * rs * g4.z + be4.z;
  float ow = (yw - mu) * rs * g4.w + be4.w;
  float4 o4; o4.x = ox; o4.y = oy; o4.z = oz; o4.w = ow;
  *(float4*)(h + (size_t)n * DD + i) = o4;
  ushort4 hbv;
  hbv.x = f2bf(ox); hbv.y = f2bf(oy); hbv.z = f2bf(oz); hbv.w = f2bf(ow);
  *(ushort4*)(hb + (size_t)n * DD + i) = hbv;
}

// ---------------- launcher ----------------

extern "C" void kernel_launch(void* const* d_in, const int* in_sizes, int n_in,
                              void* d_out, int out_size, void* d_ws, size_t ws_size,
                              hipStream_t stream) {
  (void)in_sizes; (void)n_in; (void)out_size; (void)ws_size;
  const float* x      = (const float*)d_in[0];
  const int*   EI     = (const int*)d_in[1];
  const int*   eattr  = (const int*)d_in[2];
  const int*   ntypes = (const int*)d_in[3];
  const float* ntemb  = (const float*)d_in[4];
  const float* etemb  = (const float*)d_in[5];
  const float* W_l    = (const float*)d_in[6];
  const float* b_l    = (const float*)d_in[7];
  const float* W_r    = (const float*)d_in[8];
  const float* b_r    = (const float*)d_in[9];
  const float* W_e    = (const float*)d_in[10];
  const float* att    = (const float*)d_in[11];
  const float* bias   = (const float*)d_in[12];
  const float* gamma  = (const float*)d_in[13];
  const float* beta   = (const float*)d_in[14];
  const float* W_out  = (const float*)d_in[15];
  const float* b_out  = (const float*)d_in[16];
  const float* gate   = (const float*)d_in[17];
  float* out = (float*)d_out;

  char* ws = (char*)d_ws;
  size_t off = 0;
  auto alloc = [&](size_t bytes) {
    char* p = ws + off;
    off = (off + bytes + 255) & ~(size_t)255;
    return p;
  };
  float*          h       = (float*)alloc((size_t)NN * DD * 4);
  float*          xr      = (float*)alloc((size_t)NN * DD * 4);
  unsigned short* hb      = (unsigned short*)alloc((size_t)NN * DD * 2);
  unsigned short* WTcat   = (unsigned short*)alloc((size_t)2 * DD * DD * 2);  // [W_l^T ; W_r^T]
  unsigned short* WT2     = (unsigned short*)alloc((size_t)DD * DD * 2);
  float*          Mbuf    = (float*)alloc((size_t)5 * DD * 4);
  int*            countb  = (int*)alloc((size_t)NN * 5 * 4);
  int*            rowptr  = (int*)alloc((size_t)(NN + 1) * 4);
  int*            cursor  = (int*)alloc((size_t)NN * 4);
  int*            eids    = (int*)alloc((size_t)NE * 4);
  float*          xl      = out;   // reuse d_out as xl scratch; final GEMM overwrites it

  hipMemsetAsync(countb, 0, (size_t)NN * 5 * 4, stream);
  count_kernel<<<(NE + 255) / 256, 256, 0, stream>>>(EI, eattr, countb);
  scan_kernel<<<1, 256, 0, stream>>>(countb, rowptr, cursor);
  scatter_kernel<<<(NE + 255) / 256, 256, 0, stream>>>(EI, cursor, eids);
  init_h_kernel<<<NN, 256, 0, stream>>>(x, ntypes, ntemb, h, hb);

  dim3 tgrid(DD / 32, DD / 32);
  dim3 ggrid2(16, (NN + 127) / 128);   // dual GEMM: N=2048
  dim3 ggrid1(8, (NN + 127) / 128);    // final GEMM: N=1024
  for (int l = 0; l < 2; ++l) {
    transpose_w_kernel<<<tgrid, 256, 0, stream>>>(W_l + (size_t)l * DD * DD, WTcat);
    transpose_w_kernel<<<tgrid, 256, 0, stream>>>(W_r + (size_t)l * DD * DD, WTcat + (size_t)DD * DD);
    m_kernel<<<dim3(DD / 256, 5), 256, 0, stream>>>(etemb, W_e + (size_t)l * DD * DD, Mbuf);
    gemm_bf16<<<ggrid2, 256, 0, stream>>>(hb, WTcat, b_l + l * DD, b_r + l * DD,
                                          xl, xr, nullptr, nullptr, NN, 0);
    attn_kernel<<<NN, 256, 0, stream>>>(xl, xr, EI, eattr, rowptr, eids, countb, Mbuf,
                                        att + l * DD, bias + l * DD,
                                        gamma + l * DD, beta + l * DD, h, hb);
  }
  transpose_w_kernel<<<tgrid, 256, 0, stream>>>(W_out, WT2);
  gemm_bf16<<<ggrid1, 256, 0, stream>>>(hb, WT2, b_out, nullptr,
                                        out, nullptr, x, gate, NN, 1);
}

// Round 3
// 950.700 us; speedup vs baseline: 1.6018x; 1.5479x over previous
//
#include <hip/hip_runtime.h>

// TTGNN: 2-layer GAT-style transformer conv, N=20000, E=120000, D=1024, H=8, C=128.
// R3: xl/xr stored as bf16 (halves the per-edge gather payload + GEMM writes),
// attention kernel stages (src,attr) through LDS to break dependent-load chains,
// M-table in LDS, wider scan.

#define NN 20000
#define NE 120000
#define DD 1024
#define NH 8

typedef __attribute__((ext_vector_type(4))) float f32x4;
typedef __bf16 bf16x8 __attribute__((ext_vector_type(8)));

__device__ __forceinline__ unsigned short f2bf(float f) {
  unsigned int u = __float_as_uint(f);
  u += 0x7FFFu + ((u >> 16) & 1u);   // round-to-nearest-even
  return (unsigned short)(u >> 16);
}
__device__ __forceinline__ float bf2f(unsigned short u) {
  return __uint_as_float((unsigned int)u << 16);
}

// ---------------- CSR build ----------------

__global__ __launch_bounds__(256) void count_kernel(
    const int* __restrict__ EI, const int* __restrict__ eattr, int* __restrict__ cnt) {
  int e = blockIdx.x * 256 + threadIdx.x;
  if (e < NE) {
    int d = EI[NE + e];
    int t = eattr[e];
    atomicAdd(&cnt[d * 5 + t], 1);
  }
}

__global__ __launch_bounds__(1024) void scan_kernel(
    const int* __restrict__ cnt, int* __restrict__ rowptr, int* __restrict__ cursor) {
  __shared__ int wsum[16];
  __shared__ int carry_s;
  int tid = threadIdx.x, lane = tid & 63, wv = tid >> 6;
  if (tid == 0) carry_s = 0;
  __syncthreads();
  for (int base = 0; base < NN; base += 1024) {
    int n = base + tid;
    int d = 0;
    if (n < NN) {
      const int* c = cnt + n * 5;
      d = c[0] + c[1] + c[2] + c[3] + c[4];
    }
    int v = d;
    #pragma unroll
    for (int off = 1; off < 64; off <<= 1) {
      int t = __shfl_up(v, off);
      if (lane >= off) v += t;
    }
    if (lane == 63) wsum[wv] = v;
    __syncthreads();
    int woff = 0;
    #pragma unroll
    for (int w = 0; w < 16; ++w) if (w < wv) woff += wsum[w];
    int carry = carry_s;
    int excl = carry + woff + v - d;
    if (n < NN) { rowptr[n] = excl; cursor[n] = excl; }
    __syncthreads();
    if (tid == 0) {
      int t = 0;
      #pragma unroll
      for (int w = 0; w < 16; ++w) t += wsum[w];
      carry_s = carry + t;
    }
    __syncthreads();
  }
  if (tid == 0) rowptr[NN] = carry_s;
}

__global__ __launch_bounds__(256) void scatter_kernel(
    const int* __restrict__ EI, int* __restrict__ cursor, int* __restrict__ eids) {
  int e = blockIdx.x * 256 + threadIdx.x;
  if (e < NE) {
    int d = EI[NE + e];
    int pos = atomicAdd(&cursor[d], 1);
    eids[pos] = e;
  }
}

// ---------------- h0 = x + node_type_emb[node_types] ----------------

__global__ __launch_bounds__(256) void init_h_kernel(
    const float* __restrict__ x, const int* __restrict__ ntypes,
    const float* __restrict__ ntemb, float* __restrict__ h,
    unsigned short* __restrict__ hb) {
  int idx = blockIdx.x * 256 + threadIdx.x;
  int n = idx >> 8;
  int d4 = idx & 255;
  int t = ntypes[n];
  float4 xv = ((const float4*)x)[idx];
  float4 ev = ((const float4*)ntemb)[t * 256 + d4];
  float4 o;
  o.x = xv.x + ev.x; o.y = xv.y + ev.y; o.z = xv.z + ev.z; o.w = xv.w + ev.w;
  ((float4*)h)[idx] = o;
  ushort4 hv;
  hv.x = f2bf(o.x); hv.y = f2bf(o.y); hv.z = f2bf(o.z); hv.w = f2bf(o.w);
  ((ushort4*)hb)[idx] = hv;
}

// ---------------- weight transpose + bf16: WT[n][k] = bf16(W[k][n]) ----------------

__global__ __launch_bounds__(256) void transpose_w_kernel(
    const float* __restrict__ W, unsigned short* __restrict__ WT) {
  __shared__ float tile[32][33];
  int tx = threadIdx.x & 31, ty = threadIdx.x >> 5;
  int bx = blockIdx.x * 32;   // n base
  int by = blockIdx.y * 32;   // k base
  #pragma unroll
  for (int r = 0; r < 4; ++r)
    tile[ty + r * 8][tx] = W[(size_t)(by + ty + r * 8) * DD + bx + tx];
  __syncthreads();
  #pragma unroll
  for (int r = 0; r < 4; ++r)
    WT[(size_t)(bx + ty + r * 8) * DD + by + tx] = f2bf(tile[tx][ty + r * 8]);
}

// ---------------- M[t] = edge_type_emb[t] @ W_e[l]   (5 x 1024) ----------------

__global__ __launch_bounds__(256) void m_kernel(
    const float* __restrict__ ete, const float* __restrict__ We, float* __restrict__ M) {
  int j = blockIdx.x * 256 + threadIdx.x;
  int t = blockIdx.y;
  float acc = 0.f;
  for (int k = 0; k < DD; ++k)
    acc += ete[t * DD + k] * We[(size_t)k * DD + j];
  M[t * DD + j] = acc;
}

// ---------------- bf16 MFMA GEMM, global_load_lds staging (m97 structure) ----
// A: bf16 [M][1024].  BT: bf16 [Ncols][1024] (B transposed), Ncols = 128*gridDim.x.
// mode 0 (dual): bn<8 -> bf16 C0b (+bias0), bn>=8 -> bf16 C1b (+bias1).
// mode 1 (final): fp32 C = resid + gate*(acc + bias0).

__global__ __launch_bounds__(256) void gemm_bf16(
    const unsigned short* __restrict__ A, const unsigned short* __restrict__ BT,
    const float* __restrict__ bias0, const float* __restrict__ bias1,
    void* __restrict__ C0v, void* __restrict__ C1v,
    const float* __restrict__ resid, const float* __restrict__ gatep,
    int M, int mode) {
  __shared__ unsigned short lsA[128 * 32];
  __shared__ unsigned short lsB[128 * 32];
  const int tid = threadIdx.x;
  const int lane = tid & 63;
  const int wv = tid >> 6;
  const int wm = wv & 1, wn = wv >> 1;
  const int bm = blockIdx.y, bn = blockIdx.x;
  const int row0 = bm * 128, col0 = bn * 128;
  const int l15 = lane & 15, quad = lane >> 4;

  f32x4 acc[4][4];
  #pragma unroll
  for (int mt = 0; mt < 4; ++mt)
    #pragma unroll
    for (int nt = 0; nt < 4; ++nt) {
      f32x4 z = {0.f, 0.f, 0.f, 0.f};
      acc[mt][nt] = z;
    }

  const int r_in = lane >> 2;            // 0..15
  const int kchunk = (lane & 3) * 8;     // bf16-element offset within 32-wide K

  for (int kk = 0; kk < DD; kk += 32) {
    #pragma unroll
    for (int j = 0; j < 2; ++j) {
      int r = wv * 32 + j * 16;                  // wave-uniform row base
      int gr = row0 + r + r_in;
      if (gr > M - 1) gr = M - 1;                // clamp tail (masked at store)
      const unsigned short* gpA = A + (size_t)gr * DD + kk + kchunk;
      __builtin_amdgcn_global_load_lds(
          (const __attribute__((address_space(1))) unsigned int*)gpA,
          (__attribute__((address_space(3))) unsigned int*)(lsA + r * 32), 16, 0, 0);
      const unsigned short* gpB = BT + (size_t)(col0 + r + r_in) * DD + kk + kchunk;
      __builtin_amdgcn_global_load_lds(
          (const __attribute__((address_space(1))) unsigned int*)gpB,
          (__attribute__((address_space(3))) unsigned int*)(lsB + r * 32), 16, 0, 0);
    }
    __syncthreads();
    bf16x8 af[4], bfr[4];
    #pragma unroll
    for (int mt = 0; mt < 4; ++mt)
      af[mt] = *(const bf16x8*)(lsA + (wm * 64 + mt * 16 + l15) * 32 + quad * 8);
    #pragma unroll
    for (int nt = 0; nt < 4; ++nt)
      bfr[nt] = *(const bf16x8*)(lsB + (wn * 64 + nt * 16 + l15) * 32 + quad * 8);
    #pragma unroll
    for (int mt = 0; mt < 4; ++mt)
      #pragma unroll
      for (int nt = 0; nt < 4; ++nt)
        acc[mt][nt] = __builtin_amdgcn_mfma_f32_16x16x32_bf16(af[mt], bfr[nt], acc[mt][nt], 0, 0, 0);
    __syncthreads();
  }

  if (mode == 0) {
    unsigned short* Cb = (unsigned short*)(bn < 8 ? C0v : C1v);
    const float* bp = (bn < 8) ? bias0 : bias1;
    int coff = (bn < 8) ? 0 : 1024;
    #pragma unroll
    for (int mt = 0; mt < 4; ++mt) {
      #pragma unroll
      for (int r = 0; r < 4; ++r) {
        int grow = row0 + wm * 64 + mt * 16 + quad * 4 + r;
        if (grow >= M) continue;
        #pragma unroll
        for (int nt = 0; nt < 4; ++nt) {
          int c = col0 - coff + wn * 64 + nt * 16 + l15;
          Cb[(size_t)grow * DD + c] = f2bf(acc[mt][nt][r] + bp[c]);
        }
      }
    }
  } else {
    float* Cp = (float*)C0v;
    float g = gatep[0];
    #pragma unroll
    for (int mt = 0; mt < 4; ++mt) {
      #pragma unroll
      for (int r = 0; r < 4; ++r) {
        int grow = row0 + wm * 64 + mt * 16 + quad * 4 + r;
        if (grow >= M) continue;
        #pragma unroll
        for (int nt = 0; nt < 4; ++nt) {
          int c = col0 + wn * 64 + nt * 16 + l15;
          float v = acc[mt][nt][r] + bias0[c];
          Cp[(size_t)grow * DD + c] = resid[(size_t)grow * DD + c] + g * v;
        }
      }
    }
  }
}

// ---------------- fused attention: per-node online softmax + aggregate + bias +
// ELU + residual + LayerNorm. One block (256 thr) per node; thread owns 4 channels
// (head hh = tid>>5). (src,attr) staged through LDS in chunks of 64 so row-gather
// loads are independent across iterations. xl/xr are bf16. ----------------

__global__ __launch_bounds__(256) void attn_kernel(
    const unsigned short* __restrict__ xlb, const unsigned short* __restrict__ xrb,
    const int* __restrict__ EI, const int* __restrict__ eattr,
    const int* __restrict__ rowptr, const int* __restrict__ eids,
    const int* __restrict__ cnt, const float* __restrict__ Mbuf,
    const float* __restrict__ attl, const float* __restrict__ biasl,
    const float* __restrict__ gammal, const float* __restrict__ betal,
    float* __restrict__ h, unsigned short* __restrict__ hb) {
  int n = blockIdx.x;
  int tid = threadIdx.x;
  int i = tid * 4;
  __shared__ float sM[5 * 1024];
  __shared__ int s_src[64];
  __shared__ int s_attr[64];
  __shared__ float red[8];

  {
    float4* d = (float4*)sM;
    const float4* s = (const float4*)Mbuf;
    #pragma unroll
    for (int j = 0; j < 5; ++j) d[j * 256 + tid] = s[j * 256 + tid];
  }

  float4 attv = *(const float4*)(attl + i);
  ushort4 xrb4 = *(const ushort4*)(xrb + (size_t)n * DD + i);
  float4 xrv;
  xrv.x = bf2f(xrb4.x); xrv.y = bf2f(xrb4.y); xrv.z = bf2f(xrb4.z); xrv.w = bf2f(xrb4.w);
  // residual + LN params loaded early (overlap with gather loop)
  float4 hv = *(const float4*)(h + (size_t)n * DD + i);
  float4 b4 = *(const float4*)(biasl + i);
  float4 g4 = *(const float4*)(gammal + i);
  float4 be4 = *(const float4*)(betal + i);

  // self-loop edge-emb weights: mean of incoming edge-type embeddings
  const int* c = cnt + n * 5;
  int c0 = c[0], c1 = c[1], c2 = c[2], c3 = c[3], c4 = c[4];
  float inv = 1.f / fmaxf((float)(c0 + c1 + c2 + c3 + c4), 1.f);
  float w0 = c0 * inv, w1 = c1 * inv, w2 = c2 * inv, w3 = c3 * inv, w4 = c4 * inv;
  __syncthreads();
  float4 eself;
  {
    const float* m0 = sM + 0 * 1024 + i;
    const float* m1 = sM + 1 * 1024 + i;
    const float* m2 = sM + 2 * 1024 + i;
    const float* m3 = sM + 3 * 1024 + i;
    const float* m4 = sM + 4 * 1024 + i;
    eself.x = w0 * m0[0] + w1 * m1[0] + w2 * m2[0] + w3 * m3[0] + w4 * m4[0];
    eself.y = w0 * m0[1] + w1 * m1[1] + w2 * m2[1] + w3 * m3[1] + w4 * m4[1];
    eself.z = w0 * m0[2] + w1 * m1[2] + w2 * m2[2] + w3 * m3[2] + w4 * m4[2];
    eself.w = w0 * m0[3] + w1 * m1[3] + w2 * m2[3] + w3 * m3[3] + w4 * m4[3];
  }

  float m_run = -__builtin_inff();
  float den = 0.f;
  float ax = 0.f, ay = 0.f, az = 0.f, aw = 0.f;
  int beg = rowptr[n], end = rowptr[n + 1];

  for (int base = beg; base < end; base += 64) {
    int cc = min(64, end - base);
    if (tid < cc) {
      int eid = eids[base + tid];
      s_src[tid] = EI[eid];
      s_attr[tid] = eattr[eid];
    }
    __syncthreads();
    for (int j = 0; j < cc; ++j) {
      int src = s_src[j];
      const float* ms = sM + s_attr[j] * 1024 + i;
      ushort4 vb = *(const ushort4*)(xlb + (size_t)src * DD + i);
      float vx = bf2f(vb.x), vy = bf2f(vb.y), vz = bf2f(vb.z), vw = bf2f(vb.w);
      float sx = vx + xrv.x + ms[0]; sx = sx >= 0.f ? sx : 0.2f * sx;
      float sy = vy + xrv.y + ms[1]; sy = sy >= 0.f ? sy : 0.2f * sy;
      float sz = vz + xrv.z + ms[2]; sz = sz >= 0.f ? sz : 0.2f * sz;
      float sw = vw + xrv.w + ms[3]; sw = sw >= 0.f ? sw : 0.2f * sw;
      float lg = sx * attv.x + sy * attv.y + sz * attv.z + sw * attv.w;
      lg += __shfl_xor(lg, 1);
      lg += __shfl_xor(lg, 2);
      lg += __shfl_xor(lg, 4);
      lg += __shfl_xor(lg, 8);
      lg += __shfl_xor(lg, 16);
      float mn = fmaxf(m_run, lg);
      float fs = __expf(m_run - mn);
      float p = __expf(lg - mn);
      den = den * fs + p;
      ax = ax * fs + p * vx;
      ay = ay * fs + p * vy;
      az = az * fs + p * vz;
      aw = aw * fs + p * vw;
      m_run = mn;
    }
    __syncthreads();
  }
  {  // self-loop
    ushort4 vb = *(const ushort4*)(xlb + (size_t)n * DD + i);
    float vx = bf2f(vb.x), vy = bf2f(vb.y), vz = bf2f(vb.z), vw = bf2f(vb.w);
    float sx = vx + xrv.x + eself.x; sx = sx >= 0.f ? sx : 0.2f * sx;
    float sy = vy + xrv.y + eself.y; sy = sy >= 0.f ? sy : 0.2f * sy;
    float sz = vz + xrv.z + eself.z; sz = sz >= 0.f ? sz : 0.2f * sz;
    float sw = vw + xrv.w + eself.w; sw = sw >= 0.f ? sw : 0.2f * sw;
    float lg = sx * attv.x + sy * attv.y + sz * attv.z + sw * attv.w;
    lg += __shfl_xor(lg, 1);
    lg += __shfl_xor(lg, 2);
    lg += __shfl_xor(lg, 4);
    lg += __shfl_xor(lg, 8);
    lg += __shfl_xor(lg, 16);
    float mn = fmaxf(m_run, lg);
    float fs = __expf(m_run - mn);
    float p = __expf(lg - mn);
    den = den * fs + p;
    ax = ax * fs + p * vx;
    ay = ay * fs + p * vy;
    az = az * fs + p * vz;
    aw = aw * fs + p * vw;
  }

  float invd = 1.f / den;
  ax = ax * invd + b4.x;
  ay = ay * invd + b4.y;
  az = az * invd + b4.z;
  aw = aw * invd + b4.w;
  // ELU
  ax = ax > 0.f ? ax : (__expf(ax) - 1.f);
  ay = ay > 0.f ? ay : (__expf(ay) - 1.f);
  az = az > 0.f ? az : (__expf(az) - 1.f);
  aw = aw > 0.f ? aw : (__expf(aw) - 1.f);
  // residual
  float yx = ax + hv.x, yy = ay + hv.y, yz = az + hv.z, yw = aw + hv.w;
  // LayerNorm
  float s1 = yx + yy + yz + yw;
  float s2 = yx * yx + yy * yy + yz * yz + yw * yw;
  #pragma unroll
  for (int off = 1; off < 64; off <<= 1) {
    s1 += __shfl_xor(s1, off);
    s2 += __shfl_xor(s2, off);
  }
  int lane = tid & 63, wvi = tid >> 6;
  if (lane == 0) { red[wvi] = s1; red[4 + wvi] = s2; }
  __syncthreads();
  s1 = red[0] + red[1] + red[2] + red[3];
  s2 = red[4] + red[5] + red[6] + red[7];
  float mu = s1 * (1.f / 1024.f);
  float var = s2 * (1.f / 1024.f) - mu * mu;
  float rs = rsqrtf(var + 1e-5f);
  float ox = (yx - mu) * rs * g4.x + be4.x;
  float oy = (yy - mu) * rs * g4.y + be4.y;
  float oz = (yz - mu) * rs * g4.z + be4.z;
  float ow = (yw - mu) * rs * g4.w + be4.w;
  float4 o4; o4.x = ox; o4.y = oy; o4.z = oz; o4.w = ow;
  *(float4*)(h + (size_t)n * DD + i) = o4;
  ushort4 hbv;
  hbv.x = f2bf(ox); hbv.y = f2bf(oy); hbv.z = f2bf(oz); hbv.w = f2bf(ow);
  *(ushort4*)(hb + (size_t)n * DD + i) = hbv;
}

// ---------------- launcher ----------------

extern "C" void kernel_launch(void* const* d_in, const int* in_sizes, int n_in,
                              void* d_out, int out_size, void* d_ws, size_t ws_size,
                              hipStream_t stream) {
  (void)in_sizes; (void)n_in; (void)out_size; (void)ws_size;
  const float* x      = (const float*)d_in[0];
  const int*   EI     = (const int*)d_in[1];
  const int*   eattr  = (const int*)d_in[2];
  const int*   ntypes = (const int*)d_in[3];
  const float* ntemb  = (const float*)d_in[4];
  const float* etemb  = (const float*)d_in[5];
  const float* W_l    = (const float*)d_in[6];
  const float* b_l    = (const float*)d_in[7];
  const float* W_r    = (const float*)d_in[8];
  const float* b_r    = (const float*)d_in[9];
  const float* W_e    = (const float*)d_in[10];
  const float* att    = (const float*)d_in[11];
  const float* bias   = (const float*)d_in[12];
  const float* gamma  = (const float*)d_in[13];
  const float* beta   = (const float*)d_in[14];
  const float* W_out  = (const float*)d_in[15];
  const float* b_out  = (const float*)d_in[16];
  const float* gate   = (const float*)d_in[17];
  float* out = (float*)d_out;

  char* ws = (char*)d_ws;
  size_t off = 0;
  auto alloc = [&](size_t bytes) {
    char* p = ws + off;
    off = (off + bytes + 255) & ~(size_t)255;
    return p;
  };
  float*          h       = (float*)alloc((size_t)NN * DD * 4);
  unsigned short* hb      = (unsigned short*)alloc((size_t)NN * DD * 2);
  unsigned short* xlb     = (unsigned short*)alloc((size_t)NN * DD * 2);
  unsigned short* xrb     = (unsigned short*)alloc((size_t)NN * DD * 2);
  unsigned short* WTcat   = (unsigned short*)alloc((size_t)2 * DD * DD * 2);  // [W_l^T ; W_r^T]
  unsigned short* WT2     = (unsigned short*)alloc((size_t)DD * DD * 2);
  float*          Mbuf    = (float*)alloc((size_t)5 * DD * 4);
  int*            countb  = (int*)alloc((size_t)NN * 5 * 4);
  int*            rowptr  = (int*)alloc((size_t)(NN + 1) * 4);
  int*            cursor  = (int*)alloc((size_t)NN * 4);
  int*            eids    = (int*)alloc((size_t)NE * 4);

  hipMemsetAsync(countb, 0, (size_t)NN * 5 * 4, stream);
  count_kernel<<<(NE + 255) / 256, 256, 0, stream>>>(EI, eattr, countb);
  scan_kernel<<<1, 1024, 0, stream>>>(countb, rowptr, cursor);
  scatter_kernel<<<(NE + 255) / 256, 256, 0, stream>>>(EI, cursor, eids);
  init_h_kernel<<<NN, 256, 0, stream>>>(x, ntypes, ntemb, h, hb);

  dim3 tgrid(DD / 32, DD / 32);
  dim3 ggrid2(16, (NN + 127) / 128);   // dual GEMM: N=2048
  dim3 ggrid1(8, (NN + 127) / 128);    // final GEMM: N=1024
  for (int l = 0; l < 2; ++l) {
    transpose_w_kernel<<<tgrid, 256, 0, stream>>>(W_l + (size_t)l * DD * DD, WTcat);
    transpose_w_kernel<<<tgrid, 256, 0, stream>>>(W_r + (size_t)l * DD * DD, WTcat + (size_t)DD * DD);
    m_kernel<<<dim3(DD / 256, 5), 256, 0, stream>>>(etemb, W_e + (size_t)l * DD * DD, Mbuf);
    gemm_bf16<<<ggrid2, 256, 0, stream>>>(hb, WTcat, b_l + l * DD, b_r + l * DD,
                                          xlb, xrb, nullptr, nullptr, NN, 0);
    attn_kernel<<<NN, 256, 0, stream>>>(xlb, xrb, EI, eattr, rowptr, eids, countb, Mbuf,
                                        att + l * DD, bias + l * DD,
                                        gamma + l * DD, beta + l * DD, h, hb);
  }
  transpose_w_kernel<<<tgrid, 256, 0, stream>>>(W_out, WT2);
  gemm_bf16<<<ggrid1, 256, 0, stream>>>(hb, WT2, b_out, nullptr,
                                        out, nullptr, x, gate, NN, 1);
}

// Round 4
// 947.512 us; speedup vs baseline: 1.6072x; 1.0034x over previous
//
#include <hip/hip_runtime.h>

// TTGNN: 2-layer GAT-style transformer conv, N=20000, E=120000, D=1024, H=8, C=128.
// R4: attention kernel redesigned as wave-per-node (lane owns 16 channels):
// 1 gather instr + 3 shuffles per edge (vs 4 + 20 with block-per-node), edge
// metadata broadcast via __shfl from a lane-parallel prefetch, no LDS/barriers,
// and no max-subtraction (softmax shift-invariance; logits bounded) so the
// accumulators are plain sums the compiler can pipeline.

#define NN 20000
#define NE 120000
#define DD 1024
#define NH 8

typedef __attribute__((ext_vector_type(4))) float f32x4;
typedef __bf16 bf16x8 __attribute__((ext_vector_type(8)));

__device__ __forceinline__ unsigned short f2bf(float f) {
  unsigned int u = __float_as_uint(f);
  u += 0x7FFFu + ((u >> 16) & 1u);   // round-to-nearest-even
  return (unsigned short)(u >> 16);
}
__device__ __forceinline__ float bf2f(unsigned short u) {
  return __uint_as_float((unsigned int)u << 16);
}
__device__ __forceinline__ void unpack8(uint4 u, float* f) {
  f[0] = __uint_as_float(u.x << 16); f[1] = __uint_as_float(u.x & 0xFFFF0000u);
  f[2] = __uint_as_float(u.y << 16); f[3] = __uint_as_float(u.y & 0xFFFF0000u);
  f[4] = __uint_as_float(u.z << 16); f[5] = __uint_as_float(u.z & 0xFFFF0000u);
  f[6] = __uint_as_float(u.w << 16); f[7] = __uint_as_float(u.w & 0xFFFF0000u);
}

// ---------------- CSR build ----------------

__global__ __launch_bounds__(256) void count_kernel(
    const int* __restrict__ EI, const int* __restrict__ eattr, int* __restrict__ cnt) {
  int e = blockIdx.x * 256 + threadIdx.x;
  if (e < NE) {
    int d = EI[NE + e];
    int t = eattr[e];
    atomicAdd(&cnt[d * 5 + t], 1);
  }
}

__global__ __launch_bounds__(1024) void scan_kernel(
    const int* __restrict__ cnt, int* __restrict__ rowptr, int* __restrict__ cursor) {
  __shared__ int wsum[16];
  __shared__ int carry_s;
  int tid = threadIdx.x, lane = tid & 63, wv = tid >> 6;
  if (tid == 0) carry_s = 0;
  __syncthreads();
  for (int base = 0; base < NN; base += 1024) {
    int n = base + tid;
    int d = 0;
    if (n < NN) {
      const int* c = cnt + n * 5;
      d = c[0] + c[1] + c[2] + c[3] + c[4];
    }
    int v = d;
    #pragma unroll
    for (int off = 1; off < 64; off <<= 1) {
      int t = __shfl_up(v, off);
      if (lane >= off) v += t;
    }
    if (lane == 63) wsum[wv] = v;
    __syncthreads();
    int woff = 0;
    #pragma unroll
    for (int w = 0; w < 16; ++w) if (w < wv) woff += wsum[w];
    int carry = carry_s;
    int excl = carry + woff + v - d;
    if (n < NN) { rowptr[n] = excl; cursor[n] = excl; }
    __syncthreads();
    if (tid == 0) {
      int t = 0;
      #pragma unroll
      for (int w = 0; w < 16; ++w) t += wsum[w];
      carry_s = carry + t;
    }
    __syncthreads();
  }
  if (tid == 0) rowptr[NN] = carry_s;
}

__global__ __launch_bounds__(256) void scatter_kernel(
    const int* __restrict__ EI, int* __restrict__ cursor, int* __restrict__ eids) {
  int e = blockIdx.x * 256 + threadIdx.x;
  if (e < NE) {
    int d = EI[NE + e];
    int pos = atomicAdd(&cursor[d], 1);
    eids[pos] = e;
  }
}

// ---------------- h0 = x + node_type_emb[node_types] ----------------

__global__ __launch_bounds__(256) void init_h_kernel(
    const float* __restrict__ x, const int* __restrict__ ntypes,
    const float* __restrict__ ntemb, float* __restrict__ h,
    unsigned short* __restrict__ hb) {
  int idx = blockIdx.x * 256 + threadIdx.x;
  int n = idx >> 8;
  int d4 = idx & 255;
  int t = ntypes[n];
  float4 xv = ((const float4*)x)[idx];
  float4 ev = ((const float4*)ntemb)[t * 256 + d4];
  float4 o;
  o.x = xv.x + ev.x; o.y = xv.y + ev.y; o.z = xv.z + ev.z; o.w = xv.w + ev.w;
  ((float4*)h)[idx] = o;
  ushort4 hv;
  hv.x = f2bf(o.x); hv.y = f2bf(o.y); hv.z = f2bf(o.z); hv.w = f2bf(o.w);
  ((ushort4*)hb)[idx] = hv;
}

// ---------------- weight transpose + bf16: WT[n][k] = bf16(W[k][n]) ----------------

__global__ __launch_bounds__(256) void transpose_w_kernel(
    const float* __restrict__ W, unsigned short* __restrict__ WT) {
  __shared__ float tile[32][33];
  int tx = threadIdx.x & 31, ty = threadIdx.x >> 5;
  int bx = blockIdx.x * 32;   // n base
  int by = blockIdx.y * 32;   // k base
  #pragma unroll
  for (int r = 0; r < 4; ++r)
    tile[ty + r * 8][tx] = W[(size_t)(by + ty + r * 8) * DD + bx + tx];
  __syncthreads();
  #pragma unroll
  for (int r = 0; r < 4; ++r)
    WT[(size_t)(bx + ty + r * 8) * DD + by + tx] = f2bf(tile[tx][ty + r * 8]);
}

// ---------------- M[t] = edge_type_emb[t] @ W_e[l]   (5 x 1024) ----------------

__global__ __launch_bounds__(256) void m_kernel(
    const float* __restrict__ ete, const float* __restrict__ We, float* __restrict__ M) {
  int j = blockIdx.x * 256 + threadIdx.x;
  int t = blockIdx.y;
  float acc = 0.f;
  for (int k = 0; k < DD; ++k)
    acc += ete[t * DD + k] * We[(size_t)k * DD + j];
  M[t * DD + j] = acc;
}

// ---------------- bf16 MFMA GEMM, global_load_lds staging (m97 structure) ----
// A: bf16 [M][1024].  BT: bf16 [Ncols][1024] (B transposed), Ncols = 128*gridDim.x.
// mode 0 (dual): bn<8 -> bf16 C0b (+bias0), bn>=8 -> bf16 C1b (+bias1).
// mode 1 (final): fp32 C = resid + gate*(acc + bias0).

__global__ __launch_bounds__(256) void gemm_bf16(
    const unsigned short* __restrict__ A, const unsigned short* __restrict__ BT,
    const float* __restrict__ bias0, const float* __restrict__ bias1,
    void* __restrict__ C0v, void* __restrict__ C1v,
    const float* __restrict__ resid, const float* __restrict__ gatep,
    int M, int mode) {
  __shared__ unsigned short lsA[128 * 32];
  __shared__ unsigned short lsB[128 * 32];
  const int tid = threadIdx.x;
  const int lane = tid & 63;
  const int wv = tid >> 6;
  const int wm = wv & 1, wn = wv >> 1;
  const int bm = blockIdx.y, bn = blockIdx.x;
  const int row0 = bm * 128, col0 = bn * 128;
  const int l15 = lane & 15, quad = lane >> 4;

  f32x4 acc[4][4];
  #pragma unroll
  for (int mt = 0; mt < 4; ++mt)
    #pragma unroll
    for (int nt = 0; nt < 4; ++nt) {
      f32x4 z = {0.f, 0.f, 0.f, 0.f};
      acc[mt][nt] = z;
    }

  const int r_in = lane >> 2;            // 0..15
  const int kchunk = (lane & 3) * 8;     // bf16-element offset within 32-wide K

  for (int kk = 0; kk < DD; kk += 32) {
    #pragma unroll
    for (int j = 0; j < 2; ++j) {
      int r = wv * 32 + j * 16;                  // wave-uniform row base
      int gr = row0 + r + r_in;
      if (gr > M - 1) gr = M - 1;                // clamp tail (masked at store)
      const unsigned short* gpA = A + (size_t)gr * DD + kk + kchunk;
      __builtin_amdgcn_global_load_lds(
          (const __attribute__((address_space(1))) unsigned int*)gpA,
          (__attribute__((address_space(3))) unsigned int*)(lsA + r * 32), 16, 0, 0);
      const unsigned short* gpB = BT + (size_t)(col0 + r + r_in) * DD + kk + kchunk;
      __builtin_amdgcn_global_load_lds(
          (const __attribute__((address_space(1))) unsigned int*)gpB,
          (__attribute__((address_space(3))) unsigned int*)(lsB + r * 32), 16, 0, 0);
    }
    __syncthreads();
    bf16x8 af[4], bfr[4];
    #pragma unroll
    for (int mt = 0; mt < 4; ++mt)
      af[mt] = *(const bf16x8*)(lsA + (wm * 64 + mt * 16 + l15) * 32 + quad * 8);
    #pragma unroll
    for (int nt = 0; nt < 4; ++nt)
      bfr[nt] = *(const bf16x8*)(lsB + (wn * 64 + nt * 16 + l15) * 32 + quad * 8);
    #pragma unroll
    for (int mt = 0; mt < 4; ++mt)
      #pragma unroll
      for (int nt = 0; nt < 4; ++nt)
        acc[mt][nt] = __builtin_amdgcn_mfma_f32_16x16x32_bf16(af[mt], bfr[nt], acc[mt][nt], 0, 0, 0);
    __syncthreads();
  }

  if (mode == 0) {
    unsigned short* Cb = (unsigned short*)(bn < 8 ? C0v : C1v);
    const float* bp = (bn < 8) ? bias0 : bias1;
    int coff = (bn < 8) ? 0 : 1024;
    #pragma unroll
    for (int mt = 0; mt < 4; ++mt) {
      #pragma unroll
      for (int r = 0; r < 4; ++r) {
        int grow = row0 + wm * 64 + mt * 16 + quad * 4 + r;
        if (grow >= M) continue;
        #pragma unroll
        for (int nt = 0; nt < 4; ++nt) {
          int c = col0 - coff + wn * 64 + nt * 16 + l15;
          Cb[(size_t)grow * DD + c] = f2bf(acc[mt][nt][r] + bp[c]);
        }
      }
    }
  } else {
    float* Cp = (float*)C0v;
    float g = gatep[0];
    #pragma unroll
    for (int mt = 0; mt < 4; ++mt) {
      #pragma unroll
      for (int r = 0; r < 4; ++r) {
        int grow = row0 + wm * 64 + mt * 16 + quad * 4 + r;
        if (grow >= M) continue;
        #pragma unroll
        for (int nt = 0; nt < 4; ++nt) {
          int c = col0 + wn * 64 + nt * 16 + l15;
          float v = acc[mt][nt][r] + bias0[c];
          Cp[(size_t)grow * DD + c] = resid[(size_t)grow * DD + c] + g * v;
        }
      }
    }
  }
}

// ---------------- fused attention, wave-per-node ----------------
// Block = 256 threads = 4 independent waves; wave handles node n, lane owns
// channels [lane*16, lane*16+16). Softmax computed without max-subtraction
// (shift-invariant; logits bounded by construction), so den/acc are plain sums.
// Head of a lane = lane>>3 (8 lanes per head); logit reduce = 3 xor-shuffles.

__global__ __launch_bounds__(256) void attn_kernel(
    const unsigned short* __restrict__ xlb, const unsigned short* __restrict__ xrb,
    const int* __restrict__ EI, const int* __restrict__ eattr,
    const int* __restrict__ rowptr, const int* __restrict__ eids,
    const int* __restrict__ cnt, const float* __restrict__ Mbuf,
    const float* __restrict__ attl, const float* __restrict__ biasl,
    const float* __restrict__ gammal, const float* __restrict__ betal,
    float* __restrict__ h, unsigned short* __restrict__ hb) {
  const int lane = threadIdx.x & 63;
  const int wv = threadIdx.x >> 6;
  const int n = blockIdx.x * 4 + wv;
  if (n >= NN) return;
  const int ch = lane * 16;

  float xrf[16], attf[16];
  {
    const uint4* xp = (const uint4*)(xrb + (size_t)n * DD + ch);
    uint4 a = xp[0], b = xp[1];
    unpack8(a, xrf); unpack8(b, xrf + 8);
    const float4* ap = (const float4*)(attl + ch);
    #pragma unroll
    for (int q = 0; q < 4; ++q) {
      float4 t = ap[q];
      attf[q * 4 + 0] = t.x; attf[q * 4 + 1] = t.y;
      attf[q * 4 + 2] = t.z; attf[q * 4 + 3] = t.w;
    }
  }
  float acc[16];
  #pragma unroll
  for (int c = 0; c < 16; ++c) acc[c] = 0.f;
  float den = 0.f;

  const int beg = rowptr[n], end = rowptr[n + 1];
  for (int base = beg; base < end; base += 64) {
    int cc = min(64, end - base);
    int packed = 0;
    if (lane < cc) {
      int eid = eids[base + lane];
      packed = (EI[eid] << 3) | eattr[eid];
    }
    for (int j = 0; j < cc; ++j) {
      int pk = __shfl(packed, j);
      int src = pk >> 3, at = pk & 7;
      const uint4* vp = (const uint4*)(xlb + (size_t)src * DD + ch);
      uint4 v0 = vp[0], v1 = vp[1];
      const float4* mp = (const float4*)(Mbuf + at * DD + ch);
      float vf[16];
      unpack8(v0, vf); unpack8(v1, vf + 8);
      float lg = 0.f;
      #pragma unroll
      for (int q = 0; q < 4; ++q) {
        float4 m = mp[q];
        float s0 = vf[q * 4 + 0] + xrf[q * 4 + 0] + m.x; s0 = fmaxf(s0, 0.2f * s0);
        float s1 = vf[q * 4 + 1] + xrf[q * 4 + 1] + m.y; s1 = fmaxf(s1, 0.2f * s1);
        float s2 = vf[q * 4 + 2] + xrf[q * 4 + 2] + m.z; s2 = fmaxf(s2, 0.2f * s2);
        float s3 = vf[q * 4 + 3] + xrf[q * 4 + 3] + m.w; s3 = fmaxf(s3, 0.2f * s3);
        lg += s0 * attf[q * 4 + 0] + s1 * attf[q * 4 + 1]
            + s2 * attf[q * 4 + 2] + s3 * attf[q * 4 + 3];
      }
      lg += __shfl_xor(lg, 1);
      lg += __shfl_xor(lg, 2);
      lg += __shfl_xor(lg, 4);
      float p = __expf(lg);
      den += p;
      #pragma unroll
      for (int c = 0; c < 16; ++c) acc[c] += p * vf[c];
    }
  }

  // self-loop: edge emb = mean of incoming edge-type embeddings
  {
    const int* c5 = cnt + n * 5;
    int c0 = c5[0], c1 = c5[1], c2 = c5[2], c3 = c5[3], c4 = c5[4];
    float inv = 1.f / fmaxf((float)(c0 + c1 + c2 + c3 + c4), 1.f);
    float w0 = c0 * inv, w1 = c1 * inv, w2 = c2 * inv, w3 = c3 * inv, w4 = c4 * inv;
    const uint4* vp = (const uint4*)(xlb + (size_t)n * DD + ch);
    uint4 v0 = vp[0], v1 = vp[1];
    float vf[16];
    unpack8(v0, vf); unpack8(v1, vf + 8);
    const float* m0 = Mbuf + 0 * DD + ch;
    const float* m1 = Mbuf + 1 * DD + ch;
    const float* m2 = Mbuf + 2 * DD + ch;
    const float* m3 = Mbuf + 3 * DD + ch;
    const float* m4 = Mbuf + 4 * DD + ch;
    float lg = 0.f;
    #pragma unroll
    for (int c = 0; c < 16; ++c) {
      float ee = w0 * m0[c] + w1 * m1[c] + w2 * m2[c] + w3 * m3[c] + w4 * m4[c];
      float s = vf[c] + xrf[c] + ee;
      s = fmaxf(s, 0.2f * s);
      lg += s * attf[c];
    }
    lg += __shfl_xor(lg, 1);
    lg += __shfl_xor(lg, 2);
    lg += __shfl_xor(lg, 4);
    float p = __expf(lg);
    den += p;
    #pragma unroll
    for (int c = 0; c < 16; ++c) acc[c] += p * vf[c];
  }

  // epilogue: alpha-normalize + bias + ELU + residual + LayerNorm (in-wave)
  float invd = 1.f / den;
  float y[16];
  float s1 = 0.f, s2 = 0.f;
  {
    const float4* bp = (const float4*)(biasl + ch);
    const float4* hp = (const float4*)(h + (size_t)n * DD + ch);
    #pragma unroll
    for (int q = 0; q < 4; ++q) {
      float4 b4 = bp[q];
      float4 h4 = hp[q];
      float o0 = acc[q * 4 + 0] * invd + b4.x;
      float o1 = acc[q * 4 + 1] * invd + b4.y;
      float o2 = acc[q * 4 + 2] * invd + b4.z;
      float o3 = acc[q * 4 + 3] * invd + b4.w;
      o0 = o0 > 0.f ? o0 : (__expf(o0) - 1.f);
      o1 = o1 > 0.f ? o1 : (__expf(o1) - 1.f);
      o2 = o2 > 0.f ? o2 : (__expf(o2) - 1.f);
      o3 = o3 > 0.f ? o3 : (__expf(o3) - 1.f);
      y[q * 4 + 0] = o0 + h4.x; y[q * 4 + 1] = o1 + h4.y;
      y[q * 4 + 2] = o2 + h4.z; y[q * 4 + 3] = o3 + h4.w;
      s1 += y[q * 4 + 0] + y[q * 4 + 1] + y[q * 4 + 2] + y[q * 4 + 3];
      s2 += y[q * 4 + 0] * y[q * 4 + 0] + y[q * 4 + 1] * y[q * 4 + 1]
          + y[q * 4 + 2] * y[q * 4 + 2] + y[q * 4 + 3] * y[q * 4 + 3];
    }
  }
  #pragma unroll
  for (int off = 1; off < 64; off <<= 1) {
    s1 += __shfl_xor(s1, off);
    s2 += __shfl_xor(s2, off);
  }
  float mu = s1 * (1.f / 1024.f);
  float var = s2 * (1.f / 1024.f) - mu * mu;
  float rs = rsqrtf(var + 1e-5f);
  {
    const float4* gp = (const float4*)(gammal + ch);
    const float4* bp = (const float4*)(betal + ch);
    float4* hp = (float4*)(h + (size_t)n * DD + ch);
    uint4* hbp = (uint4*)(hb + (size_t)n * DD + ch);
    uint4 pk0, pk1;
    unsigned int* pk = (unsigned int*)&pk0;
    #pragma unroll
    for (int q = 0; q < 4; ++q) {
      float4 g4 = gp[q];
      float4 b4 = bp[q];
      float4 o4;
      o4.x = (y[q * 4 + 0] - mu) * rs * g4.x + b4.x;
      o4.y = (y[q * 4 + 1] - mu) * rs * g4.y + b4.y;
      o4.z = (y[q * 4 + 2] - mu) * rs * g4.z + b4.z;
      o4.w = (y[q * 4 + 3] - mu) * rs * g4.w + b4.w;
      hp[q] = o4;
      unsigned int lo = (unsigned int)f2bf(o4.x) | ((unsigned int)f2bf(o4.y) << 16);
      unsigned int hi = (unsigned int)f2bf(o4.z) | ((unsigned int)f2bf(o4.w) << 16);
      if (q < 2) { pk[q * 2] = lo; pk[q * 2 + 1] = hi; }
      else {
        unsigned int* pkh = (unsigned int*)&pk1;
        pkh[(q - 2) * 2] = lo; pkh[(q - 2) * 2 + 1] = hi;
      }
    }
    hbp[0] = pk0;
    hbp[1] = pk1;
  }
}

// ---------------- launcher ----------------

extern "C" void kernel_launch(void* const* d_in, const int* in_sizes, int n_in,
                              void* d_out, int out_size, void* d_ws, size_t ws_size,
                              hipStream_t stream) {
  (void)in_sizes; (void)n_in; (void)out_size; (void)ws_size;
  const float* x      = (const float*)d_in[0];
  const int*   EI     = (const int*)d_in[1];
  const int*   eattr  = (const int*)d_in[2];
  const int*   ntypes = (const int*)d_in[3];
  const float* ntemb  = (const float*)d_in[4];
  const float* etemb  = (const float*)d_in[5];
  const float* W_l    = (const float*)d_in[6];
  const float* b_l    = (const float*)d_in[7];
  const float* W_r    = (const float*)d_in[8];
  const float* b_r    = (const float*)d_in[9];
  const float* W_e    = (const float*)d_in[10];
  const float* att    = (const float*)d_in[11];
  const float* bias   = (const float*)d_in[12];
  const float* gamma  = (const float*)d_in[13];
  const float* beta   = (const float*)d_in[14];
  const float* W_out  = (const float*)d_in[15];
  const float* b_out  = (const float*)d_in[16];
  const float* gate   = (const float*)d_in[17];
  float* out = (float*)d_out;

  char* ws = (char*)d_ws;
  size_t off = 0;
  auto alloc = [&](size_t bytes) {
    char* p = ws + off;
    off = (off + bytes + 255) & ~(size_t)255;
    return p;
  };
  float*          h       = (float*)alloc((size_t)NN * DD * 4);
  unsigned short* hb      = (unsigned short*)alloc((size_t)NN * DD * 2);
  unsigned short* xlb     = (unsigned short*)alloc((size_t)NN * DD * 2);
  unsigned short* xrb     = (unsigned short*)alloc((size_t)NN * DD * 2);
  unsigned short* WTcat   = (unsigned short*)alloc((size_t)2 * DD * DD * 2);  // [W_l^T ; W_r^T]
  unsigned short* WT2     = (unsigned short*)alloc((size_t)DD * DD * 2);
  float*          Mbuf    = (float*)alloc((size_t)5 * DD * 4);
  int*            countb  = (int*)alloc((size_t)NN * 5 * 4);
  int*            rowptr  = (int*)alloc((size_t)(NN + 1) * 4);
  int*            cursor  = (int*)alloc((size_t)NN * 4);
  int*            eids    = (int*)alloc((size_t)NE * 4);

  hipMemsetAsync(countb, 0, (size_t)NN * 5 * 4, stream);
  count_kernel<<<(NE + 255) / 256, 256, 0, stream>>>(EI, eattr, countb);
  scan_kernel<<<1, 1024, 0, stream>>>(countb, rowptr, cursor);
  scatter_kernel<<<(NE + 255) / 256, 256, 0, stream>>>(EI, cursor, eids);
  init_h_kernel<<<NN, 256, 0, stream>>>(x, ntypes, ntemb, h, hb);

  dim3 tgrid(DD / 32, DD / 32);
  dim3 ggrid2(16, (NN + 127) / 128);   // dual GEMM: N=2048
  dim3 ggrid1(8, (NN + 127) / 128);    // final GEMM: N=1024
  for (int l = 0; l < 2; ++l) {
    transpose_w_kernel<<<tgrid, 256, 0, stream>>>(W_l + (size_t)l * DD * DD, WTcat);
    transpose_w_kernel<<<tgrid, 256, 0, stream>>>(W_r + (size_t)l * DD * DD, WTcat + (size_t)DD * DD);
    m_kernel<<<dim3(DD / 256, 5), 256, 0, stream>>>(etemb, W_e + (size_t)l * DD * DD, Mbuf);
    gemm_bf16<<<ggrid2, 256, 0, stream>>>(hb, WTcat, b_l + l * DD, b_r + l * DD,
                                          xlb, xrb, nullptr, nullptr, NN, 0);
    attn_kernel<<<(NN + 3) / 4, 256, 0, stream>>>(xlb, xrb, EI, eattr, rowptr, eids, countb, Mbuf,
                                                  att + l * DD, bias + l * DD,
                                                  gamma + l * DD, beta + l * DD, h, hb);
  }
  transpose_w_kernel<<<tgrid, 256, 0, stream>>>(W_out, WT2);
  gemm_bf16<<<ggrid1, 256, 0, stream>>>(hb, WT2, b_out, nullptr,
                                        out, nullptr, x, gate, NN, 1);
}